// Round 6
// baseline (274.280 us; speedup 1.0000x reference)
//
#include <hip/hip_runtime.h>
#include <math.h>

#define EPSF 1.1920929e-07f

typedef __attribute__((ext_vector_type(8))) short short8;
typedef __attribute__((ext_vector_type(4))) float f32x4;

// float -> bf16 (RNE)
static __device__ __forceinline__ unsigned short f2bf(float f) {
    unsigned int u = __float_as_uint(f);
    return (unsigned short)((u + 0x7FFFu + ((u >> 16) & 1u)) >> 16);
}
static __device__ __forceinline__ float bf2f(unsigned short u) {
    return __uint_as_float((unsigned int)u << 16);
}

// ---------------------------------------------------------------------------
// prep: four block-uniform roles (unchanged from round-5 PASSED source).
// ---------------------------------------------------------------------------
__global__ __launch_bounds__(256) void prep_kernel(
    const float* __restrict__ x,
    const float* __restrict__ wg,  const float* __restrict__ wg0,
    const float* __restrict__ wg1,
    const float* __restrict__ q_w, const float* __restrict__ kv_w,
    const float* __restrict__ sr_w, const float* __restrict__ pw,
    const float* __restrict__ tbl,
    const float* __restrict__ c1w, const float* __restrict__ c1b,
    const float* __restrict__ c2w, const float* __restrict__ c2b,
    unsigned short* __restrict__ xbf, float* __restrict__ gate,
    unsigned short* __restrict__ wcat, unsigned short* __restrict__ pwbf,
    float* __restrict__ kv_wT, float* __restrict__ cpb)
{
    __shared__ float shpad[512];
    const int blk = blockIdx.x;
    const int t   = threadIdx.x;
    if (blk < 4096) {
        const int j = t & 63;                 // lane within wave; wave = row
        const int row = (blk << 2) + (t >> 6);
        float4 v = *(const float4*)(x + (size_t)row*256 + j*4);
        ushort4 o;
        o.x = f2bf(v.x); o.y = f2bf(v.y); o.z = f2bf(v.z); o.w = f2bf(v.w);
        *(ushort4*)(xbf + (size_t)row*256 + j*4) = o;
        float d[10];
#pragma unroll
        for (int f = 0; f < 10; ++f) {
            const float* wf = (f < 4) ? (wg + f*256) : (f < 6) ? (wg0 + (f-4)*256)
                                                               : (wg1 + (f-6)*256);
            float4 wv = *(const float4*)(wf + j*4);
            float s = v.x*wv.x + v.y*wv.y + v.z*wv.z + v.w*wv.w;
            s += __shfl_xor(s, 32); s += __shfl_xor(s, 16); s += __shfl_xor(s, 8);
            s += __shfl_xor(s, 4);  s += __shfl_xor(s, 2);  s += __shfl_xor(s, 1);
            d[f] = s;
        }
        if (j == 0) {
            float e[4];
            float m = fmaxf(fmaxf(d[0],d[1]), fmaxf(d[2],d[3]));
            float ssum = 0.f;
            for (int i = 0; i < 4; ++i) { e[i] = expf(d[i]-m); ssum += e[i]; }
            for (int i = 0; i < 4; ++i) e[i] /= ssum;
            int i1 = 0;
            for (int i = 1; i < 4; ++i) if (e[i] > e[i1]) i1 = i;
            int i2 = -1;
            for (int i = 0; i < 4; ++i) if (i != i1 && (i2 < 0 || e[i] > e[i2])) i2 = i;
            float rs = fmaxf(e[i1] + e[i2], EPSF);
            float rg[4] = {0.f,0.f,0.f,0.f};
            rg[i1] = e[i1] / rs * 2.f;
            rg[i2] = e[i2] / rs * 2.f;
            float sh[4];
            float m1 = fmaxf(fmaxf(d[6],d[7]), fmaxf(d[8],d[9]));
            float s1 = 0.f;
            for (int i = 0; i < 4; ++i) { sh[i] = expf(d[6+i]-m1); s1 += sh[i]; }
            float mm = fmaxf(d[4], d[5]);
            float e0 = expf(d[4]-mm), e1 = expf(d[5]-mm);
            float w00 = e0/(e0+e1)*2.f, w01 = e1/(e0+e1)*2.f;
            float* gr = gate + ((size_t)row << 3);
            for (int i = 0; i < 4; ++i) gr[i]   = w00 * (sh[i]/s1*4.f);
            for (int i = 0; i < 4; ++i) gr[4+i] = w01 * rg[i];
        }
    } else if (blk < 4416) {
        const int e = ((blk - 4096)*256 + t)*4;
        if (e < 262144) {
            int n = e >> 8, k = e & 255;
            const float* src = (n < 256) ? (q_w + n*256) :
                               (n < 768) ? (kv_w + (n-256)*256) : (sr_w + (n-768)*256);
            float4 v = *(const float4*)(src + k);
            ushort4 o;
            o.x = f2bf(v.x); o.y = f2bf(v.y); o.z = f2bf(v.z); o.w = f2bf(v.w);
            *(ushort4*)(wcat + e) = o;
        } else {
            int e2 = e - 262144;
            float4 v = *(const float4*)(pw + e2);
            ushort4 o;
            o.x = f2bf(v.x); o.y = f2bf(v.y); o.z = f2bf(v.z); o.w = f2bf(v.w);
            *(ushort4*)(pwbf + e2) = o;
        }
    } else if (blk < 4544) {
        const int e = ((blk - 4416)*256 + t)*4;     // over 131072 kv_w elems
        int o = e >> 8, k = e & 255;
        float4 v = *(const float4*)(kv_w + e);
        kv_wT[(k+0)*512 + o] = v.x;
        kv_wT[(k+1)*512 + o] = v.y;
        kv_wT[(k+2)*512 + o] = v.z;
        kv_wT[(k+3)*512 + o] = v.w;
    } else {
        const int r = blk - 4544;
        const float c0 = tbl[(size_t)r*2], c1 = tbl[(size_t)r*2+1];
        for (int i = t; i < 512; i += 256)
            shpad[i] = fmaxf(c0*c1w[i*2] + c1*c1w[i*2+1] + c1b[i], 0.f);
        __syncthreads();
        const int hh = t >> 5, dd = t & 31;
        float s = 0.f;
        for (int i = dd; i < 512; i += 32) s += shpad[i] * c2w[hh*512+i];
        for (int off = 16; off; off >>= 1) s += __shfl_xor(s, off, 32);
        // transposed [h][r] for coalesced per-head gather in attn; *log2e
        if (dd == 0) cpb[(size_t)hh*4096 + r] = (s + c2b[hh]) * 1.44269504089f;
    }
}

// ---------------------------------------------------------------------------
// MFMA bf16 GEMM, K=256, PERSISTENT-A: each block owns a 64-row A strip in
// registers (loaded ONCE) and loops over all n-tiles, staging the 32 KB B
// tile per iteration (register-prefetched; global latency hides under the
// previous tile's MFMA+epilogue). A traffic: 128 MB -> 8 MB for gemm1.
// Column-interleaved fragments (thread's 4 acc = 4 consecutive columns).
// ---------------------------------------------------------------------------
__global__ __launch_bounds__(256) void gemm_mfma(
    const unsigned short* __restrict__ A,
    const unsigned short* __restrict__ W,
    const float* __restrict__ B0, const float* __restrict__ B1,
    const float* __restrict__ B2,
    int r1, int r2, int mode, int ntiles,
    float* __restrict__ C, int ldc,
    unsigned short* __restrict__ qkv,
    const float* __restrict__ temp, const float* __restrict__ qe)
{
    __shared__ __attribute__((aligned(16))) unsigned short Bt[64*264];
    const int m0 = blockIdx.x << 6;        // 64-row strip per block
    const int t  = threadIdx.x;
    const int w  = t >> 6;
    const int col16 = t & 15;
    const int quad  = (t & 63) >> 4;

    // ---- A strip -> registers, once ----
    short8 afr[8];
    {
        const unsigned short* ap = A + (size_t)(m0 + w*16 + col16)*256 + quad*8;
#pragma unroll
        for (int kk = 0; kk < 8; ++kk)
            afr[kk] = *(const short8*)(ap + kk*32);
    }

    // staging decomposition: thread t covers chunks ci = j*256+t
    const int sr_ = t >> 5;                // base row (per j: row = j*8 + sr_)
    const int sc_ = t & 31;                // 16B chunk within row

    // ---- prefetch B tile 0 into registers ----
    uint4 Breg[8];
#pragma unroll
    for (int j = 0; j < 8; ++j)
        Breg[j] = *(const uint4*)(W + (size_t)(j*8 + sr_)*256 + sc_*8);

    for (int nt = 0; nt < ntiles; ++nt) {
        const int n0 = nt << 6;
        const int cbase = n0 + 4*col16;

        // ---- write prefetched regs -> LDS ----
#pragma unroll
        for (int j = 0; j < 8; ++j)
            *(uint4*)(Bt + (j*8 + sr_)*264 + sc_*8) = Breg[j];
        __syncthreads();

        // ---- prefetch next tile (latency hides under MFMA+epilogue) ----
        if (nt + 1 < ntiles) {
            const unsigned short* wn = W + (size_t)(nt+1)*64*256;
#pragma unroll
            for (int j = 0; j < 8; ++j)
                Breg[j] = *(const uint4*)(wn + (size_t)(j*8 + sr_)*256 + sc_*8);
        }

        // ---- per-tile scalars ----
        const float* Bp; int noff;
        if (n0 < r1)      { Bp = B0; noff = 0;  }
        else if (n0 < r2) { Bp = B1; noff = r1; }
        else              { Bp = B2; noff = r2; }
        float4 bias4 = *(const float4*)(Bp + cbase - noff);
        float bias_c[4] = {bias4.x, bias4.y, bias4.z, bias4.w};
        const int region = n0 >> 8;        // 0=q,1=k,2=v,3=sr (mode 0)
        float qe_c[4], sptv = 0.f;
        if (mode == 0 && region == 0) {
            float4 q4 = *(const float4*)(qe + cbase);
            qe_c[0]=q4.x; qe_c[1]=q4.y; qe_c[2]=q4.z; qe_c[3]=q4.w;
            sptv = log1pf(expf(temp[(cbase >> 5) & 7])) * 1.44269504089f;
        }

        // ---- MFMA (B fragment: staged rows 4*col16 + ct) ----
        f32x4 acc[4];
#pragma unroll
        for (int ct = 0; ct < 4; ++ct) acc[ct] = (f32x4){0.f, 0.f, 0.f, 0.f};
#pragma unroll
        for (int kk = 0; kk < 8; ++kk) {
#pragma unroll
            for (int ct = 0; ct < 4; ++ct) {
                short8 bf = *(const short8*)(Bt + (4*col16 + ct)*264 + kk*32 + quad*8);
                acc[ct] = __builtin_amdgcn_mfma_f32_16x16x32_bf16(afr[kk], bf, acc[ct], 0, 0, 0);
            }
        }

        // ---- epilogue ----
        if (mode == 0) {
#pragma unroll
            for (int reg = 0; reg < 4; ++reg) {
                const int row = m0 + w*16 + quad*4 + reg;
                float v[4];
#pragma unroll
                for (int c = 0; c < 4; ++c) v[c] = acc[c][reg] + bias_c[c];
                if (region <= 1) {             // q,k: per-head L2 norm
                    float s = v[0]*v[0] + v[1]*v[1] + v[2]*v[2] + v[3]*v[3];
                    s += __shfl_xor(s, 1); s += __shfl_xor(s, 2);
                    s += __shfl_xor(s, 4);
                    float inv = 1.0f / fmaxf(sqrtf(s), EPSF);
#pragma unroll
                    for (int c = 0; c < 4; ++c) v[c] *= inv;
                }
                if (region == 0) {             // q: (qn+qe)*softplus(temp)*sls*log2e
                    int n = row & 4095;
                    int y = n >> 6, x = n & 63;
                    int cs = ((y==0||y==63)?2:3) + ((x==0||x==63)?2:3);
                    float sls = (cs == 4) ? 4.2195077052f :   // ln(4+64)
                                (cs == 5) ? 4.2484952420f :   // ln(6+64)
                                            4.2904594411f;    // ln(9+64)
#pragma unroll
                    for (int c = 0; c < 4; ++c)
                        v[c] = (v[c] + qe_c[c]) * (sptv * sls);
                }
                if (region == 3) {             // sr: gelu -> f32 (float4 store)
                    float4 g4;
                    g4.x = 0.5f*v[0]*(1.0f + erff(v[0]*0.70710678118654752f));
                    g4.y = 0.5f*v[1]*(1.0f + erff(v[1]*0.70710678118654752f));
                    g4.z = 0.5f*v[2]*(1.0f + erff(v[2]*0.70710678118654752f));
                    g4.w = 0.5f*v[3]*(1.0f + erff(v[3]*0.70710678118654752f));
                    *(float4*)(C + (size_t)row * ldc + cbase) = g4;
                } else {                       // q/k/v: one ushort4 store
                    ushort4 o;
                    o.x = f2bf(v[0]); o.y = f2bf(v[1]);
                    o.z = f2bf(v[2]); o.w = f2bf(v[3]);
                    *(ushort4*)(qkv + (size_t)row * 2048 + cbase) = o;
                }
            }
        } else {
#pragma unroll
            for (int reg = 0; reg < 4; ++reg) {
                const int row = m0 + w*16 + quad*4 + reg;
                float4 o4 = {acc[0][reg] + bias_c[0], acc[1][reg] + bias_c[1],
                             acc[2][reg] + bias_c[2], acc[3][reg] + bias_c[3]};
                *(float4*)(C + (size_t)row * ldc + cbase) = o4;
            }
        }
        __syncthreads();   // all Bt reads done before next tile's write
    }
}

// ---------------------------------------------------------------------------
// fused 8x8 avg-pool + LayerNorm + pooled kv + k-norm -> bf16 pools
// (unchanged from round-5 PASSED source).
// ---------------------------------------------------------------------------
__global__ __launch_bounds__(256) void poolkv_kernel(
    const float* __restrict__ buf,
    const float* __restrict__ g, const float* __restrict__ bb,
    const float* __restrict__ kv_wT, const float* __restrict__ kv_b,
    unsigned short* __restrict__ kpb, unsigned short* __restrict__ vpb)
{
    __shared__ float xs[256];
    __shared__ float red[8];
    const int blk  = blockIdx.x;         // ((b*64+p)<<1) | half
    const int half = blk & 1;
    const int bp   = blk >> 1;
    const int b = bp >> 6, p = bp & 63;
    const int py = p >> 3, px = p & 7;
    const int t = threadIdx.x;
    const int lane = t & 63, w = t >> 6;

    float acc = 0.f;
#pragma unroll
    for (int dy = 0; dy < 8; ++dy)
#pragma unroll
        for (int dx = 0; dx < 8; ++dx) {
            int s = ((py*8+dy) << 6) + px*8 + dx;
            acc += buf[(((size_t)(b*4096+s)) << 10) + 768 + t];
        }
    acc *= (1.0f/64.0f);

    // LayerNorm stats: wave shuffle reduce + 4-slot LDS combine
    float a1 = acc, a2 = acc*acc;
    a1 += __shfl_xor(a1, 32); a2 += __shfl_xor(a2, 32);
    a1 += __shfl_xor(a1, 16); a2 += __shfl_xor(a2, 16);
    a1 += __shfl_xor(a1, 8);  a2 += __shfl_xor(a2, 8);
    a1 += __shfl_xor(a1, 4);  a2 += __shfl_xor(a2, 4);
    a1 += __shfl_xor(a1, 2);  a2 += __shfl_xor(a2, 2);
    a1 += __shfl_xor(a1, 1);  a2 += __shfl_xor(a2, 1);
    if (lane == 0) { red[w] = a1; red[4 + w] = a2; }
    __syncthreads();
    float mu = (red[0]+red[1]+red[2]+red[3]) * (1.0f/256.0f);
    float ms = (red[4]+red[5]+red[6]+red[7]) * (1.0f/256.0f);
    float rstd = rsqrtf(ms - mu*mu + 1e-5f);
    xs[t] = (acc - mu) * rstd * g[t] + bb[t];
    __syncthreads();

    // this half's kv row: 256 outputs, coalesced kv_wT[k][half*256+t] reads
    float s = kv_b[half*256 + t];
    const float* wbase = kv_wT + half*256 + t;
#pragma unroll 8
    for (int k = 0; k < 256; ++k)
        s += xs[k] * wbase[(size_t)k*512];

    const int h = t >> 5, dd = t & 31;
    const size_t ob = (size_t)(b*8+h) << 11;
    if (half == 0) {
        // per-head L2 norm: 32 consecutive t = one head = half a wave
        float s2 = s*s;
        s2 += __shfl_xor(s2, 1); s2 += __shfl_xor(s2, 2);
        s2 += __shfl_xor(s2, 4); s2 += __shfl_xor(s2, 8);
        s2 += __shfl_xor(s2, 16);
        float invn = 1.0f / fmaxf(sqrtf(s2), EPSF);
        kpb[ob + ((size_t)p << 5) + dd] = f2bf(s * invn);    // [h][p][d]
    } else {
        vpb[ob + ((size_t)dd << 6) + p] = f2bf(s);           // [h][d][p]
    }
}

// ---------------------------------------------------------------------------
// MFMA attention v7 (unchanged from round-5 PASSED source).
// ---------------------------------------------------------------------------
__global__ __launch_bounds__(256, 5) void attn_mfma(
    const unsigned short* __restrict__ qkv,
    unsigned short* __restrict__ ao,
    const unsigned short* __restrict__ kpb,
    const unsigned short* __restrict__ vpb,
    const float* __restrict__ cpb,
    const int*   __restrict__ rpi,
    const float* __restrict__ temp,
    const float* __restrict__ qe,
    const float* __restrict__ rpb,
    const float* __restrict__ lt,
    const float* __restrict__ lb,
    const float* __restrict__ gate)
{
    __shared__ __attribute__((aligned(16))) unsigned char SMEM[32624];
    unsigned short* U0  = (unsigned short*)SMEM;             // KH [112][40]=8960 | VT [32][136]=8704
    unsigned short* U1  = (unsigned short*)(SMEM + 8960);    // KP [64][40]=5120  | VPT [32][72]=4608
    unsigned short* P   = (unsigned short*)(SMEM + 14080);   // [64][136]=17408
    unsigned short* LTT = (unsigned short*)(SMEM + 31488);   // [16][32]=1024
    float* dqvL = (float*)(SMEM + 32512);                    // 16 f
    float* rpbL = (float*)(SMEM + 32576);                    // 9 f (dyn-indexed)

    const int tile = blockIdx.x;
    const int h    = blockIdx.y;
    const int b    = blockIdx.z;
    const int ty0  = (tile >> 3) << 3;
    const int tx0  = (tile & 7) << 3;
    const int t    = threadIdx.x;
    const int lane  = t & 63;
    const int w     = t >> 6;
    const int col16 = lane & 15;
    const int quad  = lane >> 4;
    const int s_w   = (20*w) & ~15;

    // ---- early per-lane direct Q fragment load ----
    const int nq = w*16 + col16;
    const int qy = ty0 + (nq >> 3), qx = tx0 + (nq & 7);
    short8 aq = *(const short8*)(qkv +
        ((size_t)(b*4096 + ((qy<<6)|qx)))*2048 + h*32 + quad*8);

    // ---- early rpi loads, then direct L2 cpb gathers (hidden under QK) ----
    int rpv[4][4];
#pragma unroll
    for (int ct = 0; ct < 4; ++ct) {
        int p = ct*16 + col16;
#pragma unroll
        for (int reg = 0; reg < 4; ++reg) {
            int n = w*16 + quad*4 + reg;
            int y = ty0 + (n >> 3), x = tx0 + (n & 7);
            rpv[ct][reg] = rpi[(size_t)((y << 6) | x)*64 + p];
        }
    }
    const float* cpbh = cpb + (size_t)h*4096;
    float pbias[4][4];
#pragma unroll
    for (int ct = 0; ct < 4; ++ct)
#pragma unroll
        for (int reg = 0; reg < 4; ++reg)
            pbias[ct][reg] = cpbh[rpv[ct][reg]];

    // ---- gate prefetch (independent; consumed at the very end) ----
    float gv[4];
#pragma unroll
    for (int reg = 0; reg < 4; ++reg) {
        int n = w*16 + quad*4 + reg;
        int y = ty0 + (n >> 3), x = tx0 + (n & 7);
        gv[reg] = gate[(((size_t)(b*4096 + ((y<<6)|x))) << 3) + h];
    }

    // ---- K halo -> LDS (inline offsets, issued pre-barrier) ----
    for (int i = t; i < 896; i += 256) {
        int r = i >> 3, sg = i & 7;
        uint2 val = {0u, 0u};
        if (r < 100) {
            int y = ty0 + r/10 - 1, x = tx0 + r%10 - 1;
            if (y >= 0 && y < 64 && x >= 0 && x < 64)
                val = *(const uint2*)(qkv +
                    (size_t)(b*4096 + ((y<<6)|x))*2048 + h*32 + 256 + sg*4);
        }
        *(uint2*)(U0 + r*40 + sg*4) = val;
    }
    // ---- K pool -> LDS ----
    {
        const unsigned short* src = kpb + (size_t)(b*8+h)*2048;
        for (int i = t; i < 512; i += 256)
            *(uint2*)(U1 + (i >> 3)*40 + (i & 7)*4) = *(const uint2*)(src + i*4);
    }
    const float spt  = log1pf(expf(temp[h]));
    const float sptL = spt * 1.44269504089f;
    if (t >= 64 && t < 80) {
        int j = t - 64;
        float s = 0.f;
        if (j < 9) {
            s = lb[h*9 + j];
            for (int dd = 0; dd < 32; ++dd)
                s -= qe[h*32+dd] * lt[(h*32+dd)*9 + j];
        }
        dqvL[j] = s;
    } else if (t >= 80 && t < 89) {
        rpbL[t-80] = rpb[h*9 + (t-80)] * 1.44269504089f;   // log2 domain
    }
    for (int i = t; i < 512; i += 256) {
        int j = i >> 5, dd = i & 31;
        LTT[j*32 + dd] = (j < 9) ? f2bf(lt[(h*32+dd)*9 + j]) : (unsigned short)0;
    }
    __syncthreads();

    f32x4 cl[4], cp[4];
    {
        const f32x4 z = {0.f, 0.f, 0.f, 0.f};
#pragma unroll
        for (int ct = 0; ct < 4; ++ct) {
            short8 bk = *(const short8*)(U0 + (s_w + ct*16 + col16)*40 + quad*8);
            cl[ct] = __builtin_amdgcn_mfma_f32_16x16x32_bf16(aq, bk, z, 0, 0, 0);
        }
#pragma unroll
        for (int ct = 0; ct < 4; ++ct) {
            short8 bp = *(const short8*)(U1 + (ct*16 + col16)*40 + quad*8);
            cp[ct] = __builtin_amdgcn_mfma_f32_16x16x32_bf16(aq, bp, z, 0, 0, 0);
        }
    }
#pragma unroll
    for (int ct = 0; ct < 4; ++ct) {
        int hk = s_w + ct*16 + col16;
        int ky = hk / 10, kx = hk - ky*10;
#pragma unroll
        for (int reg = 0; reg < 4; ++reg) {
            int n = w*16 + quad*4 + reg;
            int dy = ky - (n >> 3), dx = kx - (n & 7);
            bool valid = (dy >= 0 && dy <= 2 && dx >= 0 && dx <= 2);
            cl[ct][reg] = valid ? (cl[ct][reg] + rpbL[dy*3 + dx]) : -1e30f;
        }
    }
#pragma unroll
    for (int ct = 0; ct < 4; ++ct)
#pragma unroll
        for (int reg = 0; reg < 4; ++reg)
            cp[ct][reg] += pbias[ct][reg];

    float inv[4];
#pragma unroll
    for (int reg = 0; reg < 4; ++reg) {
        float m = -1e30f;
#pragma unroll
        for (int ct = 0; ct < 4; ++ct) m = fmaxf(m, cl[ct][reg]);
#pragma unroll
        for (int ct = 0; ct < 4; ++ct) m = fmaxf(m, cp[ct][reg]);
        m = fmaxf(m, __shfl_xor(m, 1)); m = fmaxf(m, __shfl_xor(m, 2));
        m = fmaxf(m, __shfl_xor(m, 4)); m = fmaxf(m, __shfl_xor(m, 8));
        float s = 0.f;
#pragma unroll
        for (int ct = 0; ct < 4; ++ct) {
            float e = exp2f(cl[ct][reg] - m); cl[ct][reg] = e; s += e;
        }
#pragma unroll
        for (int ct = 0; ct < 4; ++ct) {
            float e = exp2f(cp[ct][reg] - m); cp[ct][reg] = e; s += e;
        }
        s += __shfl_xor(s, 1); s += __shfl_xor(s, 2);
        s += __shfl_xor(s, 4); s += __shfl_xor(s, 8);
        inv[reg] = 1.0f / s;
    }
#pragma unroll
    for (int ct = 0; ct < 4; ++ct)
#pragma unroll
        for (int reg = 0; reg < 4; ++reg) {
            int n = w*16 + quad*4 + reg;
            P[n*136 + ct*16 + col16] = f2bf(cl[ct][reg] * inv[reg]);
        }
#pragma unroll
    for (int ct = 0; ct < 4; ++ct)
#pragma unroll
        for (int reg = 0; reg < 4; ++reg) {
            int n = w*16 + quad*4 + reg;
            P[n*136 + 64 + ct*16 + col16] = f2bf(cp[ct][reg] * inv[reg]);
        }
    {
        const f32x4 z = {0.f, 0.f, 0.f, 0.f};
        short8 blt = *(const short8*)(LTT + col16*32 + quad*8);
        f32x4 cd = __builtin_amdgcn_mfma_f32_16x16x32_bf16(aq, blt, z, 0, 0, 0);
        if (col16 < 9) {
            // sls has only 3 possible values -> constant select
            const float iA = 1.0f / (sptL * 4.2195077052f);  // ln(4+64)
            const float iB = 1.0f / (sptL * 4.2484952420f);  // ln(6+64)
            const float iC = 1.0f / (sptL * 4.2904594411f);  // ln(9+64)
            int dy = col16 / 3, dx = col16 - dy*3;
#pragma unroll
            for (int reg = 0; reg < 4; ++reg) {
                int n = w*16 + quad*4 + reg;
                int y = ty0 + (n >> 3), x = tx0 + (n & 7);
                int cs = ((y==0||y==63)?2:3) + ((x==0||x==63)?2:3);
                float isc = (cs == 4) ? iA : (cs == 5) ? iB : iC;
                float ltv = cd[reg] * isc + dqvL[col16];
                int hk = ((n >> 3) + dy)*10 + (n & 7) + dx;
                int pc = hk - s_w;
                P[n*136 + pc] = f2bf(bf2f(P[n*136 + pc]) + ltv);
            }
        }
    }
    __syncthreads();

    unsigned short* VT  = U0;   // [32][136]
    unsigned short* VPT = U1;   // [32][72]
    for (int i = t; i < 896; i += 256) {
        int r = i >> 3, sg = i & 7;
        uint2 val = {0u, 0u};
        if (r < 100) {
            int y = ty0 + r/10 - 1, x = tx0 + r%10 - 1;
            if (y >= 0 && y < 64 && x >= 0 && x < 64)
                val = *(const uint2*)(qkv +
                    (size_t)(b*4096 + ((y<<6)|x))*2048 + h*32 + 512 + sg*4);
        }
        int d0 = sg << 2;
        VT[(d0+0)*136 + r] = (unsigned short)(val.x & 0xffffu);
        VT[(d0+1)*136 + r] = (unsigned short)(val.x >> 16);
        VT[(d0+2)*136 + r] = (unsigned short)(val.y & 0xffffu);
        VT[(d0+3)*136 + r] = (unsigned short)(val.y >> 16);
    }
    {   // vpb is pre-transposed [h][d][p]: coalesced copy
        const unsigned short* vsrc = vpb + (size_t)(b*8+h)*2048;
        for (int i = t; i < 512; i += 256) {
            int d = i >> 4, p4 = (i & 15) << 2;
            *(uint2*)(VPT + d*72 + p4) = *(const uint2*)(vsrc + d*64 + p4);
        }
    }
    __syncthreads();

    f32x4 o0 = {0.f,0.f,0.f,0.f}, o1 = {0.f,0.f,0.f,0.f};
#pragma unroll
    for (int ks = 0; ks < 4; ++ks) {
        short8 a = *(const short8*)(P + (w*16 + col16)*136 + ks*32 + quad*8);
        short8 b0, b1;
        if (ks < 2) {
            b0 = *(const short8*)(VT + col16*136      + s_w + ks*32 + quad*8);
            b1 = *(const short8*)(VT + (16+col16)*136 + s_w + ks*32 + quad*8);
        } else {
            b0 = *(const short8*)(VPT + col16*72      + (ks-2)*32 + quad*8);
            b1 = *(const short8*)(VPT + (16+col16)*72 + (ks-2)*32 + quad*8);
        }
        o0 = __builtin_amdgcn_mfma_f32_16x16x32_bf16(a, b0, o0, 0, 0, 0);
        o1 = __builtin_amdgcn_mfma_f32_16x16x32_bf16(a, b1, o1, 0, 0, 0);
    }
#pragma unroll
    for (int reg = 0; reg < 4; ++reg) {
        int n = w*16 + quad*4 + reg;
        int y = ty0 + (n >> 3), x = tx0 + (n & 7);
        size_t rowo = (size_t)(b*4096 + ((y<<6)|x))*256 + h*32;
        float g = gv[reg];
        ao[rowo + col16]      = f2bf(o0[reg] * g);
        ao[rowo + 16 + col16] = f2bf(o1[reg] * g);
    }
}

// ---------------------------------------------------------------------------
extern "C" void kernel_launch(void* const* d_in, const int* in_sizes, int n_in,
                              void* d_out, int out_size, void* d_ws, size_t ws_size,
                              hipStream_t stream)
{
    const float* x    = (const float*)d_in[0];
    const float* tbl  = (const float*)d_in[1];
    const float* q_w  = (const float*)d_in[2];
    const float* q_b  = (const float*)d_in[3];
    const float* kv_w = (const float*)d_in[4];
    const float* kv_b = (const float*)d_in[5];
    const float* temp = (const float*)d_in[6];
    const float* qe   = (const float*)d_in[7];
    const float* rpb  = (const float*)d_in[8];
    const float* lt   = (const float*)d_in[9];
    const float* lb   = (const float*)d_in[10];
    const float* c1w  = (const float*)d_in[11];
    const float* c1b  = (const float*)d_in[12];
    const float* c2w  = (const float*)d_in[13];
    const float* c2b  = (const float*)d_in[14];
    const float* sr_w = (const float*)d_in[15];
    const float* sr_b = (const float*)d_in[16];
    const float* ng   = (const float*)d_in[17];
    const float* nbias= (const float*)d_in[18];
    const float* wg   = (const float*)d_in[19];
    const float* wg0  = (const float*)d_in[20];
    const float* wg1  = (const float*)d_in[21];
    const float* pw   = (const float*)d_in[22];
    const float* pb   = (const float*)d_in[23];
    const int*   rpi  = (const int*)d_in[24];
    (void)in_sizes; (void)n_in; (void)out_size; (void)ws_size;

    float* buf   = (float*)d_ws;                       // 16384x1024 f32 layout
    unsigned short* qkvb = (unsigned short*)d_ws;      // (16384, 2048) ushort view
    float* xp    = buf + (size_t)16384*1024;
    float* kpoolf= xp + 65536;
    unsigned short* kpb = (unsigned short*)kpoolf;
    unsigned short* vpb = kpb + 131072;
    float* cpbb  = kpoolf + 131072;
    float* gateb = cpbb + 32768;
    float* kvwT  = gateb + 131072;                     // 131072 f32 (512 KB)
    unsigned short* xbf  = (unsigned short*)(kvwT + 131072);
    unsigned short* ao   = xbf;                        // reuses x_bf (dead after gemm1)
    unsigned short* wcat = xbf + (size_t)16384*256;
    unsigned short* pwbf = wcat + 262144;
    float* out   = (float*)d_out;

    // 1) prep: x->bf16 + gates | weights->bf16 | kv_w transpose | cpb table
    prep_kernel<<<8640,256,0,stream>>>(x, wg, wg0, wg1, q_w, kv_w, sr_w, pw,
                                       tbl, c1w, c1b, c2w, c2b,
                                       xbf, gateb, wcat, pwbf, kvwT, cpbb);
    // 2) fused MFMA GEMM, persistent-A: A read once, loop 16 n-tiles
    gemm_mfma<<<256,256,0,stream>>>(xbf, wcat, q_b, kv_b, sr_b,
                                    256, 768, 0, 16, buf, 1024,
                                    qkvb, temp, qe);
    // 3) pool + LN + pooled kv (512 blocks: k-half / v-half split)
    poolkv_kernel<<<512,256,0,stream>>>(buf, ng, nbias, kvwT, kv_b, kpb, vpb);
    // 4) MFMA attention v7 -> bf16 compact
    attn_mfma<<<dim3(64,8,4),256,0,stream>>>(qkvb, ao, kpb, vpb, cpbb, rpi,
                                             temp, qe, rpb, lt, lb, gateb);
    // 5) output projection (persistent-A, 4 n-tiles)
    gemm_mfma<<<256,256,0,stream>>>(ao, pwbf, pb, pb, pb,
                                    1<<30, 1<<30, 1, 4, out, 256,
                                    (unsigned short*)nullptr, nullptr, nullptr);
}

// Round 7
// 218.578 us; speedup vs baseline: 1.2548x; 1.2548x over previous
//
#include <hip/hip_runtime.h>
#include <math.h>

#define EPSF 1.1920929e-07f

typedef __attribute__((ext_vector_type(8))) short short8;
typedef __attribute__((ext_vector_type(4))) float f32x4;

// float -> bf16 (RNE)
static __device__ __forceinline__ unsigned short f2bf(float f) {
    unsigned int u = __float_as_uint(f);
    return (unsigned short)((u + 0x7FFFu + ((u >> 16) & 1u)) >> 16);
}
static __device__ __forceinline__ float bf2f(unsigned short u) {
    return __uint_as_float((unsigned int)u << 16);
}

// ---------------------------------------------------------------------------
// prep: four block-uniform roles (unchanged from round-5 PASSED source).
// ---------------------------------------------------------------------------
__global__ __launch_bounds__(256) void prep_kernel(
    const float* __restrict__ x,
    const float* __restrict__ wg,  const float* __restrict__ wg0,
    const float* __restrict__ wg1,
    const float* __restrict__ q_w, const float* __restrict__ kv_w,
    const float* __restrict__ sr_w, const float* __restrict__ pw,
    const float* __restrict__ tbl,
    const float* __restrict__ c1w, const float* __restrict__ c1b,
    const float* __restrict__ c2w, const float* __restrict__ c2b,
    unsigned short* __restrict__ xbf, float* __restrict__ gate,
    unsigned short* __restrict__ wcat, unsigned short* __restrict__ pwbf,
    float* __restrict__ kv_wT, float* __restrict__ cpb)
{
    __shared__ float shpad[512];
    const int blk = blockIdx.x;
    const int t   = threadIdx.x;
    if (blk < 4096) {
        const int j = t & 63;                 // lane within wave; wave = row
        const int row = (blk << 2) + (t >> 6);
        float4 v = *(const float4*)(x + (size_t)row*256 + j*4);
        ushort4 o;
        o.x = f2bf(v.x); o.y = f2bf(v.y); o.z = f2bf(v.z); o.w = f2bf(v.w);
        *(ushort4*)(xbf + (size_t)row*256 + j*4) = o;
        float d[10];
#pragma unroll
        for (int f = 0; f < 10; ++f) {
            const float* wf = (f < 4) ? (wg + f*256) : (f < 6) ? (wg0 + (f-4)*256)
                                                               : (wg1 + (f-6)*256);
            float4 wv = *(const float4*)(wf + j*4);
            float s = v.x*wv.x + v.y*wv.y + v.z*wv.z + v.w*wv.w;
            s += __shfl_xor(s, 32); s += __shfl_xor(s, 16); s += __shfl_xor(s, 8);
            s += __shfl_xor(s, 4);  s += __shfl_xor(s, 2);  s += __shfl_xor(s, 1);
            d[f] = s;
        }
        if (j == 0) {
            float e[4];
            float m = fmaxf(fmaxf(d[0],d[1]), fmaxf(d[2],d[3]));
            float ssum = 0.f;
            for (int i = 0; i < 4; ++i) { e[i] = expf(d[i]-m); ssum += e[i]; }
            for (int i = 0; i < 4; ++i) e[i] /= ssum;
            int i1 = 0;
            for (int i = 1; i < 4; ++i) if (e[i] > e[i1]) i1 = i;
            int i2 = -1;
            for (int i = 0; i < 4; ++i) if (i != i1 && (i2 < 0 || e[i] > e[i2])) i2 = i;
            float rs = fmaxf(e[i1] + e[i2], EPSF);
            float rg[4] = {0.f,0.f,0.f,0.f};
            rg[i1] = e[i1] / rs * 2.f;
            rg[i2] = e[i2] / rs * 2.f;
            float sh[4];
            float m1 = fmaxf(fmaxf(d[6],d[7]), fmaxf(d[8],d[9]));
            float s1 = 0.f;
            for (int i = 0; i < 4; ++i) { sh[i] = expf(d[6+i]-m1); s1 += sh[i]; }
            float mm = fmaxf(d[4], d[5]);
            float e0 = expf(d[4]-mm), e1 = expf(d[5]-mm);
            float w00 = e0/(e0+e1)*2.f, w01 = e1/(e0+e1)*2.f;
            float* gr = gate + ((size_t)row << 3);
            for (int i = 0; i < 4; ++i) gr[i]   = w00 * (sh[i]/s1*4.f);
            for (int i = 0; i < 4; ++i) gr[4+i] = w01 * rg[i];
        }
    } else if (blk < 4416) {
        const int e = ((blk - 4096)*256 + t)*4;
        if (e < 262144) {
            int n = e >> 8, k = e & 255;
            const float* src = (n < 256) ? (q_w + n*256) :
                               (n < 768) ? (kv_w + (n-256)*256) : (sr_w + (n-768)*256);
            float4 v = *(const float4*)(src + k);
            ushort4 o;
            o.x = f2bf(v.x); o.y = f2bf(v.y); o.z = f2bf(v.z); o.w = f2bf(v.w);
            *(ushort4*)(wcat + e) = o;
        } else {
            int e2 = e - 262144;
            float4 v = *(const float4*)(pw + e2);
            ushort4 o;
            o.x = f2bf(v.x); o.y = f2bf(v.y); o.z = f2bf(v.z); o.w = f2bf(v.w);
            *(ushort4*)(pwbf + e2) = o;
        }
    } else if (blk < 4544) {
        const int e = ((blk - 4416)*256 + t)*4;     // over 131072 kv_w elems
        int o = e >> 8, k = e & 255;
        float4 v = *(const float4*)(kv_w + e);
        kv_wT[(k+0)*512 + o] = v.x;
        kv_wT[(k+1)*512 + o] = v.y;
        kv_wT[(k+2)*512 + o] = v.z;
        kv_wT[(k+3)*512 + o] = v.w;
    } else {
        const int r = blk - 4544;
        const float c0 = tbl[(size_t)r*2], c1 = tbl[(size_t)r*2+1];
        for (int i = t; i < 512; i += 256)
            shpad[i] = fmaxf(c0*c1w[i*2] + c1*c1w[i*2+1] + c1b[i], 0.f);
        __syncthreads();
        const int hh = t >> 5, dd = t & 31;
        float s = 0.f;
        for (int i = dd; i < 512; i += 32) s += shpad[i] * c2w[hh*512+i];
        for (int off = 16; off; off >>= 1) s += __shfl_xor(s, off, 32);
        // transposed [h][r] for coalesced per-head gather in attn; *log2e
        if (dd == 0) cpb[(size_t)hh*4096 + r] = (s + c2b[hh]) * 1.44269504089f;
    }
}

// ---------------------------------------------------------------------------
// MFMA bf16 GEMM, K=256. 128x64 output per block (two m-tiles share one
// B-stage + barrier). EXACT round-5 PASSED structure (2048/512 blocks,
// 4 blocks/CU — reverted from the 1-block/CU persistent-A regression).
// ---------------------------------------------------------------------------
__global__ __launch_bounds__(256) void gemm_mfma(
    const unsigned short* __restrict__ A,
    const unsigned short* __restrict__ W,
    const float* __restrict__ B0, const float* __restrict__ B1,
    const float* __restrict__ B2,
    int r1, int r2, int mode,
    float* __restrict__ C, int ldc,
    unsigned short* __restrict__ qkv,
    const float* __restrict__ temp, const float* __restrict__ qe)
{
    __shared__ __attribute__((aligned(16))) unsigned short Bt[64*264];
    const int m0b = blockIdx.y << 7;       // two 64-row tiles per block
    const int n0  = blockIdx.x << 6;
    const int t   = threadIdx.x;
    const int w   = t >> 6;
    const int col16 = t & 15;
    const int quad  = (t & 63) >> 4;
    const int cbase = n0 + 4*col16;        // this thread's first output column

    const float* Bp; int noff;
    if (n0 < r1)      { Bp = B0; noff = 0;  }
    else if (n0 < r2) { Bp = B1; noff = r1; }
    else              { Bp = B2; noff = r2; }

    // ---- A strip (tile 0) -> registers ----
    short8 afrA[8];
    {
        const unsigned short* ap = A + (size_t)(m0b + w*16 + col16)*256 + quad*8;
#pragma unroll
        for (int kk = 0; kk < 8; ++kk)
            afrA[kk] = *(const short8*)(ap + kk*32);
    }
    // ---- stage B tile once (8 uint4 per thread), one barrier ----
#pragma unroll
    for (int j = 0; j < 8; ++j) {
        int ci = j*256 + t;            // 16B chunk: row = ci>>5, chunk = ci&31
        int r = ci >> 5, c = ci & 31;
        uint4 bv = *(const uint4*)(W + (size_t)(n0 + r)*256 + c*8);
        *(uint4*)(Bt + r*264 + c*8) = bv;
    }
    __syncthreads();

    float4 bias4 = *(const float4*)(Bp + cbase - noff);
    float bias_c[4] = {bias4.x, bias4.y, bias4.z, bias4.w};

    const int region = n0 >> 8;        // 0=q, 1=k, 2=v, 3=sr (mode 0 only)
    float qe_c[4], sptv = 0.f;
    if (mode == 0 && region == 0) {
        float4 q4 = *(const float4*)(qe + cbase);
        qe_c[0]=q4.x; qe_c[1]=q4.y; qe_c[2]=q4.z; qe_c[3]=q4.w;
        // all 4 cols in one head (cbase%32 in {0,4,...,28})
        sptv = log1pf(expf(temp[(cbase >> 5) & 7])) * 1.44269504089f;
    }

    auto epilogue = [&](f32x4* acc, int m0) {
        if (mode == 0) {
#pragma unroll
            for (int reg = 0; reg < 4; ++reg) {
                const int row = m0 + w*16 + quad*4 + reg;
                float v[4];
#pragma unroll
                for (int c = 0; c < 4; ++c) v[c] = acc[c][reg] + bias_c[c];
                if (region <= 1) {             // q,k: per-head L2 norm
                    // head = 8-lane group (cols 4*col16..+3): 3-shuffle reduce
                    float s = v[0]*v[0] + v[1]*v[1] + v[2]*v[2] + v[3]*v[3];
                    s += __shfl_xor(s, 1); s += __shfl_xor(s, 2);
                    s += __shfl_xor(s, 4);
                    float inv = 1.0f / fmaxf(sqrtf(s), EPSF);
#pragma unroll
                    for (int c = 0; c < 4; ++c) v[c] *= inv;
                }
                if (region == 0) {             // q: (qn+qe)*softplus(temp)*sls*log2e
                    int n = row & 4095;
                    int y = n >> 6, x = n & 63;
                    int cs = ((y==0||y==63)?2:3) + ((x==0||x==63)?2:3);
                    float sls = (cs == 4) ? 4.2195077052f :   // ln(4+64)
                                (cs == 5) ? 4.2484952420f :   // ln(6+64)
                                            4.2904594411f;    // ln(9+64)
#pragma unroll
                    for (int c = 0; c < 4; ++c)
                        v[c] = (v[c] + qe_c[c]) * (sptv * sls);
                }
                if (region == 3) {             // sr: gelu -> f32 (float4 store)
                    float4 g4;
                    g4.x = 0.5f*v[0]*(1.0f + erff(v[0]*0.70710678118654752f));
                    g4.y = 0.5f*v[1]*(1.0f + erff(v[1]*0.70710678118654752f));
                    g4.z = 0.5f*v[2]*(1.0f + erff(v[2]*0.70710678118654752f));
                    g4.w = 0.5f*v[3]*(1.0f + erff(v[3]*0.70710678118654752f));
                    *(float4*)(C + (size_t)row * ldc + cbase) = g4;
                } else {                       // q/k/v: one ushort4 store
                    ushort4 o;
                    o.x = f2bf(v[0]); o.y = f2bf(v[1]);
                    o.z = f2bf(v[2]); o.w = f2bf(v[3]);
                    *(ushort4*)(qkv + (size_t)row * 2048 + cbase) = o;
                }
            }
        } else {
#pragma unroll
            for (int reg = 0; reg < 4; ++reg) {
                const int row = m0 + w*16 + quad*4 + reg;
                float4 o4 = {acc[0][reg] + bias_c[0], acc[1][reg] + bias_c[1],
                             acc[2][reg] + bias_c[2], acc[3][reg] + bias_c[3]};
                *(float4*)(C + (size_t)row * ldc + cbase) = o4;
            }
        }
    };

    // ---- tile 0 MFMA (B fragment: rows 4*col16 + ct) ----
    f32x4 acc[4];
#pragma unroll
    for (int ct = 0; ct < 4; ++ct) acc[ct] = (f32x4){0.f, 0.f, 0.f, 0.f};
#pragma unroll
    for (int kk = 0; kk < 8; ++kk) {
#pragma unroll
        for (int ct = 0; ct < 4; ++ct) {
            short8 bf = *(const short8*)(Bt + (4*col16 + ct)*264 + kk*32 + quad*8);
            acc[ct] = __builtin_amdgcn_mfma_f32_16x16x32_bf16(afrA[kk], bf, acc[ct], 0, 0, 0);
        }
    }
    // ---- A strip (tile 1): issue loads now; epilogue-0 hides the latency ----
    short8 afrB[8];
    {
        const unsigned short* ap = A + (size_t)(m0b + 64 + w*16 + col16)*256 + quad*8;
#pragma unroll
        for (int kk = 0; kk < 8; ++kk)
            afrB[kk] = *(const short8*)(ap + kk*32);
    }
    epilogue(acc, m0b);

    // ---- tile 1 MFMA ----
#pragma unroll
    for (int ct = 0; ct < 4; ++ct) acc[ct] = (f32x4){0.f, 0.f, 0.f, 0.f};
#pragma unroll
    for (int kk = 0; kk < 8; ++kk) {
#pragma unroll
        for (int ct = 0; ct < 4; ++ct) {
            short8 bf = *(const short8*)(Bt + (4*col16 + ct)*264 + kk*32 + quad*8);
            acc[ct] = __builtin_amdgcn_mfma_f32_16x16x32_bf16(afrB[kk], bf, acc[ct], 0, 0, 0);
        }
    }
    epilogue(acc, m0b + 64);
}

// ---------------------------------------------------------------------------
// poolkv v3: ONE 512-thread block per (b,p). Pool split across thread-halves
// (32 loads/thread -> buf traffic halved vs the 2-block split), LayerNorm
// computed ONCE, then each of the 512 threads produces one kv output
// (same total GEMM work / same 8 waves-per-CU parallelism as before).
// ---------------------------------------------------------------------------
__global__ __launch_bounds__(512) void poolkv_kernel(
    const float* __restrict__ buf,
    const float* __restrict__ g, const float* __restrict__ bb,
    const float* __restrict__ kv_wT, const float* __restrict__ kv_b,
    unsigned short* __restrict__ kpb, unsigned short* __restrict__ vpb)
{
    __shared__ float part[512];
    __shared__ float xs[256];
    __shared__ float red[8];
    const int blk = blockIdx.x;          // b*64+p
    const int b = blk >> 6, p = blk & 63;
    const int py = p >> 3, px = p & 7;
    const int t = threadIdx.x;
    const int c  = t & 255;              // channel
    const int hi = t >> 8;               // dy half (0: dy 0-3, 1: dy 4-7)

    float acc = 0.f;
#pragma unroll
    for (int i = 0; i < 4; ++i) {
        int dy = hi*4 + i;
#pragma unroll
        for (int dx = 0; dx < 8; ++dx) {
            int s = ((py*8+dy) << 6) + px*8 + dx;
            acc += buf[(((size_t)(b*4096+s)) << 10) + 768 + c];
        }
    }
    part[t] = acc;
    __syncthreads();

    float av = 0.f;
    if (t < 256) {
        av = (part[t] + part[t+256]) * (1.0f/64.0f);
        // LayerNorm stats: wave shuffle reduce + 4-slot LDS combine
        float a1 = av, a2 = av*av;
        a1 += __shfl_xor(a1, 32); a2 += __shfl_xor(a2, 32);
        a1 += __shfl_xor(a1, 16); a2 += __shfl_xor(a2, 16);
        a1 += __shfl_xor(a1, 8);  a2 += __shfl_xor(a2, 8);
        a1 += __shfl_xor(a1, 4);  a2 += __shfl_xor(a2, 4);
        a1 += __shfl_xor(a1, 2);  a2 += __shfl_xor(a2, 2);
        a1 += __shfl_xor(a1, 1);  a2 += __shfl_xor(a2, 1);
        if ((t & 63) == 0) { red[t >> 6] = a1; red[4 + (t >> 6)] = a2; }
    }
    __syncthreads();
    if (t < 256) {
        float mu = (red[0]+red[1]+red[2]+red[3]) * (1.0f/256.0f);
        float ms = (red[4]+red[5]+red[6]+red[7]) * (1.0f/256.0f);
        float rstd = rsqrtf(ms - mu*mu + 1e-5f);
        xs[t] = (av - mu) * rstd * g[t] + bb[t];
    }
    __syncthreads();

    // kv row: 512 outputs (one per thread), coalesced kv_wT[k][t] reads
    float s = kv_b[t];
    const float* wbase = kv_wT + t;
#pragma unroll 8
    for (int k = 0; k < 256; ++k)
        s += xs[k] * wbase[(size_t)k*512];

    if (t < 256) {
        // k half: per-head L2 norm (32 consecutive t = one head = half-wave)
        const int h = t >> 5, dd = t & 31;
        float s2 = s*s;
        s2 += __shfl_xor(s2, 1); s2 += __shfl_xor(s2, 2);
        s2 += __shfl_xor(s2, 4); s2 += __shfl_xor(s2, 8);
        s2 += __shfl_xor(s2, 16);
        float invn = 1.0f / fmaxf(sqrtf(s2), EPSF);
        kpb[(((size_t)(b*8+h)) << 11) + ((size_t)p << 5) + dd] = f2bf(s * invn); // [h][p][d]
    } else {
        const int c2 = t - 256;
        const int h = c2 >> 5, dd = c2 & 31;
        vpb[(((size_t)(b*8+h)) << 11) + ((size_t)dd << 6) + p] = f2bf(s);        // [h][d][p]
    }
}

// ---------------------------------------------------------------------------
// MFMA attention v7 (unchanged from round-5 PASSED source).
// ---------------------------------------------------------------------------
__global__ __launch_bounds__(256, 5) void attn_mfma(
    const unsigned short* __restrict__ qkv,
    unsigned short* __restrict__ ao,
    const unsigned short* __restrict__ kpb,
    const unsigned short* __restrict__ vpb,
    const float* __restrict__ cpb,
    const int*   __restrict__ rpi,
    const float* __restrict__ temp,
    const float* __restrict__ qe,
    const float* __restrict__ rpb,
    const float* __restrict__ lt,
    const float* __restrict__ lb,
    const float* __restrict__ gate)
{
    __shared__ __attribute__((aligned(16))) unsigned char SMEM[32624];
    unsigned short* U0  = (unsigned short*)SMEM;             // KH [112][40]=8960 | VT [32][136]=8704
    unsigned short* U1  = (unsigned short*)(SMEM + 8960);    // KP [64][40]=5120  | VPT [32][72]=4608
    unsigned short* P   = (unsigned short*)(SMEM + 14080);   // [64][136]=17408
    unsigned short* LTT = (unsigned short*)(SMEM + 31488);   // [16][32]=1024
    float* dqvL = (float*)(SMEM + 32512);                    // 16 f
    float* rpbL = (float*)(SMEM + 32576);                    // 9 f (dyn-indexed)

    const int tile = blockIdx.x;
    const int h    = blockIdx.y;
    const int b    = blockIdx.z;
    const int ty0  = (tile >> 3) << 3;
    const int tx0  = (tile & 7) << 3;
    const int t    = threadIdx.x;
    const int lane  = t & 63;
    const int w     = t >> 6;
    const int col16 = lane & 15;
    const int quad  = lane >> 4;
    const int s_w   = (20*w) & ~15;

    // ---- early per-lane direct Q fragment load ----
    const int nq = w*16 + col16;
    const int qy = ty0 + (nq >> 3), qx = tx0 + (nq & 7);
    short8 aq = *(const short8*)(qkv +
        ((size_t)(b*4096 + ((qy<<6)|qx)))*2048 + h*32 + quad*8);

    // ---- early rpi loads, then direct L2 cpb gathers (hidden under QK) ----
    int rpv[4][4];
#pragma unroll
    for (int ct = 0; ct < 4; ++ct) {
        int p = ct*16 + col16;
#pragma unroll
        for (int reg = 0; reg < 4; ++reg) {
            int n = w*16 + quad*4 + reg;
            int y = ty0 + (n >> 3), x = tx0 + (n & 7);
            rpv[ct][reg] = rpi[(size_t)((y << 6) | x)*64 + p];
        }
    }
    const float* cpbh = cpb + (size_t)h*4096;
    float pbias[4][4];
#pragma unroll
    for (int ct = 0; ct < 4; ++ct)
#pragma unroll
        for (int reg = 0; reg < 4; ++reg)
            pbias[ct][reg] = cpbh[rpv[ct][reg]];

    // ---- gate prefetch (independent; consumed at the very end) ----
    float gv[4];
#pragma unroll
    for (int reg = 0; reg < 4; ++reg) {
        int n = w*16 + quad*4 + reg;
        int y = ty0 + (n >> 3), x = tx0 + (n & 7);
        gv[reg] = gate[(((size_t)(b*4096 + ((y<<6)|x))) << 3) + h];
    }

    // ---- K halo -> LDS (inline offsets, issued pre-barrier) ----
    for (int i = t; i < 896; i += 256) {
        int r = i >> 3, sg = i & 7;
        uint2 val = {0u, 0u};
        if (r < 100) {
            int y = ty0 + r/10 - 1, x = tx0 + r%10 - 1;
            if (y >= 0 && y < 64 && x >= 0 && x < 64)
                val = *(const uint2*)(qkv +
                    (size_t)(b*4096 + ((y<<6)|x))*2048 + h*32 + 256 + sg*4);
        }
        *(uint2*)(U0 + r*40 + sg*4) = val;
    }
    // ---- K pool -> LDS ----
    {
        const unsigned short* src = kpb + (size_t)(b*8+h)*2048;
        for (int i = t; i < 512; i += 256)
            *(uint2*)(U1 + (i >> 3)*40 + (i & 7)*4) = *(const uint2*)(src + i*4);
    }
    const float spt  = log1pf(expf(temp[h]));
    const float sptL = spt * 1.44269504089f;
    if (t >= 64 && t < 80) {
        int j = t - 64;
        float s = 0.f;
        if (j < 9) {
            s = lb[h*9 + j];
            for (int dd = 0; dd < 32; ++dd)
                s -= qe[h*32+dd] * lt[(h*32+dd)*9 + j];
        }
        dqvL[j] = s;
    } else if (t >= 80 && t < 89) {
        rpbL[t-80] = rpb[h*9 + (t-80)] * 1.44269504089f;   // log2 domain
    }
    for (int i = t; i < 512; i += 256) {
        int j = i >> 5, dd = i & 31;
        LTT[j*32 + dd] = (j < 9) ? f2bf(lt[(h*32+dd)*9 + j]) : (unsigned short)0;
    }
    __syncthreads();

    f32x4 cl[4], cp[4];
    {
        const f32x4 z = {0.f, 0.f, 0.f, 0.f};
#pragma unroll
        for (int ct = 0; ct < 4; ++ct) {
            short8 bk = *(const short8*)(U0 + (s_w + ct*16 + col16)*40 + quad*8);
            cl[ct] = __builtin_amdgcn_mfma_f32_16x16x32_bf16(aq, bk, z, 0, 0, 0);
        }
#pragma unroll
        for (int ct = 0; ct < 4; ++ct) {
            short8 bp = *(const short8*)(U1 + (ct*16 + col16)*40 + quad*8);
            cp[ct] = __builtin_amdgcn_mfma_f32_16x16x32_bf16(aq, bp, z, 0, 0, 0);
        }
    }
#pragma unroll
    for (int ct = 0; ct < 4; ++ct) {
        int hk = s_w + ct*16 + col16;
        int ky = hk / 10, kx = hk - ky*10;
#pragma unroll
        for (int reg = 0; reg < 4; ++reg) {
            int n = w*16 + quad*4 + reg;
            int dy = ky - (n >> 3), dx = kx - (n & 7);
            bool valid = (dy >= 0 && dy <= 2 && dx >= 0 && dx <= 2);
            cl[ct][reg] = valid ? (cl[ct][reg] + rpbL[dy*3 + dx]) : -1e30f;
        }
    }
#pragma unroll
    for (int ct = 0; ct < 4; ++ct)
#pragma unroll
        for (int reg = 0; reg < 4; ++reg)
            cp[ct][reg] += pbias[ct][reg];

    float inv[4];
#pragma unroll
    for (int reg = 0; reg < 4; ++reg) {
        float m = -1e30f;
#pragma unroll
        for (int ct = 0; ct < 4; ++ct) m = fmaxf(m, cl[ct][reg]);
#pragma unroll
        for (int ct = 0; ct < 4; ++ct) m = fmaxf(m, cp[ct][reg]);
        m = fmaxf(m, __shfl_xor(m, 1)); m = fmaxf(m, __shfl_xor(m, 2));
        m = fmaxf(m, __shfl_xor(m, 4)); m = fmaxf(m, __shfl_xor(m, 8));
        float s = 0.f;
#pragma unroll
        for (int ct = 0; ct < 4; ++ct) {
            float e = exp2f(cl[ct][reg] - m); cl[ct][reg] = e; s += e;
        }
#pragma unroll
        for (int ct = 0; ct < 4; ++ct) {
            float e = exp2f(cp[ct][reg] - m); cp[ct][reg] = e; s += e;
        }
        s += __shfl_xor(s, 1); s += __shfl_xor(s, 2);
        s += __shfl_xor(s, 4); s += __shfl_xor(s, 8);
        inv[reg] = 1.0f / s;
    }
#pragma unroll
    for (int ct = 0; ct < 4; ++ct)
#pragma unroll
        for (int reg = 0; reg < 4; ++reg) {
            int n = w*16 + quad*4 + reg;
            P[n*136 + ct*16 + col16] = f2bf(cl[ct][reg] * inv[reg]);
        }
#pragma unroll
    for (int ct = 0; ct < 4; ++ct)
#pragma unroll
        for (int reg = 0; reg < 4; ++reg) {
            int n = w*16 + quad*4 + reg;
            P[n*136 + 64 + ct*16 + col16] = f2bf(cp[ct][reg] * inv[reg]);
        }
    {
        const f32x4 z = {0.f, 0.f, 0.f, 0.f};
        short8 blt = *(const short8*)(LTT + col16*32 + quad*8);
        f32x4 cd = __builtin_amdgcn_mfma_f32_16x16x32_bf16(aq, blt, z, 0, 0, 0);
        if (col16 < 9) {
            // sls has only 3 possible values -> constant select
            const float iA = 1.0f / (sptL * 4.2195077052f);  // ln(4+64)
            const float iB = 1.0f / (sptL * 4.2484952420f);  // ln(6+64)
            const float iC = 1.0f / (sptL * 4.2904594411f);  // ln(9+64)
            int dy = col16 / 3, dx = col16 - dy*3;
#pragma unroll
            for (int reg = 0; reg < 4; ++reg) {
                int n = w*16 + quad*4 + reg;
                int y = ty0 + (n >> 3), x = tx0 + (n & 7);
                int cs = ((y==0||y==63)?2:3) + ((x==0||x==63)?2:3);
                float isc = (cs == 4) ? iA : (cs == 5) ? iB : iC;
                float ltv = cd[reg] * isc + dqvL[col16];
                int hk = ((n >> 3) + dy)*10 + (n & 7) + dx;
                int pc = hk - s_w;
                P[n*136 + pc] = f2bf(bf2f(P[n*136 + pc]) + ltv);
            }
        }
    }
    __syncthreads();

    unsigned short* VT  = U0;   // [32][136]
    unsigned short* VPT = U1;   // [32][72]
    for (int i = t; i < 896; i += 256) {
        int r = i >> 3, sg = i & 7;
        uint2 val = {0u, 0u};
        if (r < 100) {
            int y = ty0 + r/10 - 1, x = tx0 + r%10 - 1;
            if (y >= 0 && y < 64 && x >= 0 && x < 64)
                val = *(const uint2*)(qkv +
                    (size_t)(b*4096 + ((y<<6)|x))*2048 + h*32 + 512 + sg*4);
        }
        int d0 = sg << 2;
        VT[(d0+0)*136 + r] = (unsigned short)(val.x & 0xffffu);
        VT[(d0+1)*136 + r] = (unsigned short)(val.x >> 16);
        VT[(d0+2)*136 + r] = (unsigned short)(val.y & 0xffffu);
        VT[(d0+3)*136 + r] = (unsigned short)(val.y >> 16);
    }
    {   // vpb is pre-transposed [h][d][p]: coalesced copy
        const unsigned short* vsrc = vpb + (size_t)(b*8+h)*2048;
        for (int i = t; i < 512; i += 256) {
            int d = i >> 4, p4 = (i & 15) << 2;
            *(uint2*)(VPT + d*72 + p4) = *(const uint2*)(vsrc + d*64 + p4);
        }
    }
    __syncthreads();

    f32x4 o0 = {0.f,0.f,0.f,0.f}, o1 = {0.f,0.f,0.f,0.f};
#pragma unroll
    for (int ks = 0; ks < 4; ++ks) {
        short8 a = *(const short8*)(P + (w*16 + col16)*136 + ks*32 + quad*8);
        short8 b0, b1;
        if (ks < 2) {
            b0 = *(const short8*)(VT + col16*136      + s_w + ks*32 + quad*8);
            b1 = *(const short8*)(VT + (16+col16)*136 + s_w + ks*32 + quad*8);
        } else {
            b0 = *(const short8*)(VPT + col16*72      + (ks-2)*32 + quad*8);
            b1 = *(const short8*)(VPT + (16+col16)*72 + (ks-2)*32 + quad*8);
        }
        o0 = __builtin_amdgcn_mfma_f32_16x16x32_bf16(a, b0, o0, 0, 0, 0);
        o1 = __builtin_amdgcn_mfma_f32_16x16x32_bf16(a, b1, o1, 0, 0, 0);
    }
#pragma unroll
    for (int reg = 0; reg < 4; ++reg) {
        int n = w*16 + quad*4 + reg;
        int y = ty0 + (n >> 3), x = tx0 + (n & 7);
        size_t rowo = (size_t)(b*4096 + ((y<<6)|x))*256 + h*32;
        float g = gv[reg];
        ao[rowo + col16]      = f2bf(o0[reg] * g);
        ao[rowo + 16 + col16] = f2bf(o1[reg] * g);
    }
}

// ---------------------------------------------------------------------------
extern "C" void kernel_launch(void* const* d_in, const int* in_sizes, int n_in,
                              void* d_out, int out_size, void* d_ws, size_t ws_size,
                              hipStream_t stream)
{
    const float* x    = (const float*)d_in[0];
    const float* tbl  = (const float*)d_in[1];
    const float* q_w  = (const float*)d_in[2];
    const float* q_b  = (const float*)d_in[3];
    const float* kv_w = (const float*)d_in[4];
    const float* kv_b = (const float*)d_in[5];
    const float* temp = (const float*)d_in[6];
    const float* qe   = (const float*)d_in[7];
    const float* rpb  = (const float*)d_in[8];
    const float* lt   = (const float*)d_in[9];
    const float* lb   = (const float*)d_in[10];
    const float* c1w  = (const float*)d_in[11];
    const float* c1b  = (const float*)d_in[12];
    const float* c2w  = (const float*)d_in[13];
    const float* c2b  = (const float*)d_in[14];
    const float* sr_w = (const float*)d_in[15];
    const float* sr_b = (const float*)d_in[16];
    const float* ng   = (const float*)d_in[17];
    const float* nbias= (const float*)d_in[18];
    const float* wg   = (const float*)d_in[19];
    const float* wg0  = (const float*)d_in[20];
    const float* wg1  = (const float*)d_in[21];
    const float* pw   = (const float*)d_in[22];
    const float* pb   = (const float*)d_in[23];
    const int*   rpi  = (const int*)d_in[24];
    (void)in_sizes; (void)n_in; (void)out_size; (void)ws_size;

    float* buf   = (float*)d_ws;                       // 16384x1024 f32 layout
    unsigned short* qkvb = (unsigned short*)d_ws;      // (16384, 2048) ushort view
    float* xp    = buf + (size_t)16384*1024;
    float* kpoolf= xp + 65536;
    unsigned short* kpb = (unsigned short*)kpoolf;
    unsigned short* vpb = kpb + 131072;
    float* cpbb  = kpoolf + 131072;
    float* gateb = cpbb + 32768;
    float* kvwT  = gateb + 131072;                     // 131072 f32 (512 KB)
    unsigned short* xbf  = (unsigned short*)(kvwT + 131072);
    unsigned short* ao   = xbf;                        // reuses x_bf (dead after gemm1)
    unsigned short* wcat = xbf + (size_t)16384*256;
    unsigned short* pwbf = wcat + 262144;
    float* out   = (float*)d_out;

    // 1) prep: x->bf16 + gates | weights->bf16 | kv_w transpose | cpb table
    prep_kernel<<<8640,256,0,stream>>>(x, wg, wg0, wg1, q_w, kv_w, sr_w, pw,
                                       tbl, c1w, c1b, c2w, c2b,
                                       xbf, gateb, wcat, pwbf, kvwT, cpbb);
    // 2) fused MFMA GEMM (128x64 per block, round-5 structure restored)
    gemm_mfma<<<dim3(16,128),256,0,stream>>>(xbf, wcat, q_b, kv_b, sr_b,
                                             256, 768, 0, buf, 1024,
                                             qkvb, temp, qe);
    // 3) pool + LN + pooled kv (one 512-thread block per (b,p))
    poolkv_kernel<<<256,512,0,stream>>>(buf, ng, nbias, kvwT, kv_b, kpb, vpb);
    // 4) MFMA attention v7 -> bf16 compact
    attn_mfma<<<dim3(64,8,4),256,0,stream>>>(qkvb, ao, kpb, vpb, cpbb, rpi,
                                             temp, qe, rpb, lt, lb, gateb);
    // 5) output projection (round-5 structure restored)
    gemm_mfma<<<dim3(4,128),256,0,stream>>>(ao, pwbf, pb, pb, pb,
                                            1<<30, 1<<30, 1, out, 256,
                                            (unsigned short*)nullptr, nullptr, nullptr);
}